// Round 1
// baseline (163.202 us; speedup 1.0000x reference)
//
#include <hip/hip_runtime.h>

#define HID 256
#define NB 8
#define SQL 2048
#define SKV 2048
#define KVBLK 64
#define NST (SKV / KVBLK)

typedef __attribute__((ext_vector_type(8))) short bf16x8;
typedef __attribute__((ext_vector_type(4))) float f32x4;
typedef __attribute__((ext_vector_type(4))) unsigned int u32x4;

static __device__ __forceinline__ unsigned short f2bf(float x) {
  union { float f; unsigned int u; } v; v.f = x;
  unsigned int r = v.u + 0x7FFFu + ((v.u >> 16) & 1u);
  return (unsigned short)(r >> 16);
}

// ---------- P0: convert weight matrices to bf16 ----------
__global__ void wconv_kernel(const float* __restrict__ Wq, const float* __restrict__ Wk,
                             const float* __restrict__ Wv, unsigned short* __restrict__ out) {
  int i = blockIdx.x * blockDim.x + threadIdx.x;
  if (i >= 3 * HID * HID) return;
  const float* src = (i < HID * HID) ? Wq : (i < 2 * HID * HID ? Wk : Wv);
  out[i] = f2bf(src[i & (HID * HID - 1)]);
}

// ---------- P1: QKV projection (bf16 MFMA), V written transposed ----------
__global__ __launch_bounds__(256) void proj_kernel(
    const float* __restrict__ query, const float* __restrict__ key, const float* __restrict__ value,
    const unsigned short* __restrict__ Wb,
    const float* __restrict__ bq, const float* __restrict__ bk, const float* __restrict__ bv,
    unsigned short* __restrict__ Qb, unsigned short* __restrict__ Kb, unsigned short* __restrict__ Vtb) {
  int blk = blockIdx.x;
  int mat = blk >> 8;      // 0:Q 1:K 2:V
  int rem = blk & 255;
  int b = rem >> 5;
  int st = rem & 31;       // 64-row tile
  int tid = threadIdx.x;
  int wave = tid >> 6, lane = tid & 63, lr = lane & 15, lg = lane >> 4;

  const float* X = (mat == 0) ? query : (mat == 1 ? key : value);
  const float* bias = (mat == 0) ? bq : (mat == 1 ? bk : bv);
  const unsigned short* W = Wb + mat * HID * HID;

  int row_a = st * 64 + wave * 16 + lr;
  const float* xrow = X + ((size_t)(b * SQL + row_a)) * HID;
  bf16x8 af[8];
#pragma unroll
  for (int s = 0; s < 8; s++) {
    const float4* p = (const float4*)(xrow + s * 32 + lg * 8);
    float4 x0 = p[0], x1 = p[1];
    bf16x8 a;
    a[0] = (short)f2bf(x0.x); a[1] = (short)f2bf(x0.y); a[2] = (short)f2bf(x0.z); a[3] = (short)f2bf(x0.w);
    a[4] = (short)f2bf(x1.x); a[5] = (short)f2bf(x1.y); a[6] = (short)f2bf(x1.z); a[7] = (short)f2bf(x1.w);
    af[s] = a;
  }
  int row_c = st * 64 + wave * 16 + lg * 4;

#pragma unroll
  for (int eg = 0; eg < 4; eg++) {
    f32x4 a4[4];
#pragma unroll
    for (int e4 = 0; e4 < 4; e4++) a4[e4] = (f32x4){0.f, 0.f, 0.f, 0.f};
#pragma unroll
    for (int sl = 0; sl < 8; sl++) {
#pragma unroll
      for (int e4 = 0; e4 < 4; e4++) {
        const unsigned short* wrow = W + ((eg * 4 + e4) * 16 + lr) * HID;
        bf16x8 bfr = *(const bf16x8*)(wrow + sl * 32 + lg * 8);
        a4[e4] = __builtin_amdgcn_mfma_f32_16x16x32_bf16(af[sl], bfr, a4[e4], 0, 0, 0);
      }
    }
#pragma unroll
    for (int e4 = 0; e4 < 4; e4++) {
      int e = (eg * 4 + e4) * 16 + lr;
      float bv_ = bias[e];
      if (mat < 2) {
        unsigned short* dst = (mat == 0 ? Qb : Kb) + (size_t)(b * SQL) * HID;
#pragma unroll
        for (int i = 0; i < 4; i++)
          dst[(size_t)(row_c + i) * HID + e] = f2bf(a4[e4][i] + bv_);
      } else {
        ushort4 v;
        v.x = f2bf(a4[e4][0] + bv_); v.y = f2bf(a4[e4][1] + bv_);
        v.z = f2bf(a4[e4][2] + bv_); v.w = f2bf(a4[e4][3] + bv_);
        *(ushort4*)(Vtb + ((size_t)(b * HID + e)) * SKV + row_c) = v;
      }
    }
  }
}

// ---------- A: flash attention, bf16 MFMA, dbuf swizzled LDS ----------
__global__ __launch_bounds__(256, 1) void attn_kernel(
    const unsigned short* __restrict__ Qb, const unsigned short* __restrict__ Kb,
    const unsigned short* __restrict__ Vtb, float* __restrict__ out) {
  extern __shared__ char smem[];
  // [0,65536): K bufs 2x32KB ; [65536,131072): Vt bufs 2x32KB ; [131072,139264): P per-wave 2KB
  int tid = threadIdx.x;
  int wave = tid >> 6, lane = tid & 63, lr = lane & 15, lg = lane >> 4;
  int b = blockIdx.x >> 5;
  int q0 = (blockIdx.x & 31) * 64;

  const unsigned short* Kbb = Kb + (size_t)b * SKV * HID;
  const unsigned short* Vbb = Vtb + (size_t)b * HID * SKV;

  bf16x8 qf[8];
  {
    const unsigned short* qrow = Qb + ((size_t)(b * SQL + q0 + wave * 16 + lr)) * HID;
#pragma unroll
    for (int s = 0; s < 8; s++) qf[s] = *(const bf16x8*)(qrow + s * 32 + lg * 8);
  }

  f32x4 acc[16];
#pragma unroll
  for (int dt = 0; dt < 16; dt++) acc[dt] = (f32x4){0.f, 0.f, 0.f, 0.f};
  float m_[4] = {-1e30f, -1e30f, -1e30f, -1e30f};
  float l_[4] = {0.f, 0.f, 0.f, 0.f};

  char* pbase = smem + 131072 + wave * 2048;
  const float kC = 1.44269504088896341f / 11.3137084989847604f;  // log2(e)/sqrt(128)
  int swzk = (lr & 7) << 4;

  u32x4 stg[16];
  auto sload = [&](int k0) {
#pragma unroll
    for (int i = 0; i < 8; i++) {
      int u = tid + i * 256; int r = u >> 5, c = u & 31;
      stg[i] = *(const u32x4*)(Kbb + (size_t)(k0 + r) * HID + c * 8);
    }
#pragma unroll
    for (int i = 0; i < 8; i++) {
      int u = tid + i * 256; int d = u >> 3, c = u & 7;
      stg[8 + i] = *(const u32x4*)(Vbb + (size_t)d * SKV + k0 + c * 8);
    }
  };
  auto swrite = [&](int buf) {
    char* kb = smem + buf * 32768;
    char* vb = smem + 65536 + buf * 32768;
#pragma unroll
    for (int i = 0; i < 8; i++) {
      int u = tid + i * 256; int r = u >> 5, c = u & 31;
      *(u32x4*)(kb + r * 512 + ((c * 16) ^ ((r & 7) << 4))) = stg[i];
    }
#pragma unroll
    for (int i = 0; i < 8; i++) {
      int u = tid + i * 256; int d = u >> 3, c = u & 7;
      *(u32x4*)(vb + d * 128 + ((c * 16) ^ ((d & 7) << 4))) = stg[8 + i];
    }
  };

  sload(0); swrite(0); __syncthreads();

  for (int t = 0; t < NST; t++) {
    int cur = t & 1;
    if (t + 1 < NST) sload((t + 1) * KVBLK);

    char* kb = smem + cur * 32768;
    char* vb = smem + 65536 + cur * 32768;

    // QK^T: 4 independent 16x16 score tiles, K=256 in 8 slices
    f32x4 sc[4];
#pragma unroll
    for (int jt = 0; jt < 4; jt++) sc[jt] = (f32x4){0.f, 0.f, 0.f, 0.f};
#pragma unroll
    for (int sl = 0; sl < 8; sl++) {
#pragma unroll
      for (int jt = 0; jt < 4; jt++) {
        bf16x8 kf = *(const bf16x8*)(kb + (jt * 16 + lr) * 512 + ((sl * 64 + lg * 16) ^ swzk));
        sc[jt] = __builtin_amdgcn_mfma_f32_16x16x32_bf16(qf[sl], kf, sc[jt], 0, 0, 0);
      }
    }
#pragma unroll
    for (int jt = 0; jt < 4; jt++)
#pragma unroll
      for (int i = 0; i < 4; i++) sc[jt][i] *= kC;

    // online softmax (rows live on 16 lanes: col=lane&15, row=lg*4+i)
    float sf[4];
    int need = 0;
#pragma unroll
    for (int i = 0; i < 4; i++) {
      float v = fmaxf(fmaxf(sc[0][i], sc[1][i]), fmaxf(sc[2][i], sc[3][i]));
#pragma unroll
      for (int d = 1; d < 16; d <<= 1) v = fmaxf(v, __shfl_xor(v, d, 64));
      need |= (v > m_[i]) ? 1 : 0;
      float mn = fmaxf(m_[i], v);
      sf[i] = exp2f(m_[i] - mn);
      m_[i] = mn;
    }
#pragma unroll
    for (int jt = 0; jt < 4; jt++)
#pragma unroll
      for (int i = 0; i < 4; i++) sc[jt][i] = exp2f(sc[jt][i] - m_[i]);
#pragma unroll
    for (int i = 0; i < 4; i++) {
      float v = sc[0][i] + sc[1][i] + sc[2][i] + sc[3][i];
#pragma unroll
      for (int d = 1; d < 16; d <<= 1) v += __shfl_xor(v, d, 64);
      l_[i] = l_[i] * sf[i] + v;
    }
    if (__any(need)) {
#pragma unroll
      for (int dt = 0; dt < 16; dt++)
#pragma unroll
        for (int i = 0; i < 4; i++) acc[dt][i] *= sf[i];
    }

    // P -> LDS (bf16, swizzled) to convert C-layout -> A-layout
#pragma unroll
    for (int jt = 0; jt < 4; jt++) {
      int key = jt * 16 + lr;
#pragma unroll
      for (int i = 0; i < 4; i++) {
        int r = lg * 4 + i;
        *(unsigned short*)(pbase + r * 128 + ((key * 2) ^ ((r & 7) << 4))) = f2bf(sc[jt][i]);
      }
    }

    // PV: O[16x256] += P[16x64] * V[64x256]
#pragma unroll
    for (int ks = 0; ks < 2; ks++) {
      bf16x8 pf = *(const bf16x8*)(pbase + lr * 128 + ((ks * 64 + lg * 16) ^ swzk));
#pragma unroll
      for (int dt = 0; dt < 16; dt++) {
        bf16x8 vf = *(const bf16x8*)(vb + (dt * 16 + lr) * 128 + ((ks * 64 + lg * 16) ^ swzk));
        acc[dt] = __builtin_amdgcn_mfma_f32_16x16x32_bf16(pf, vf, acc[dt], 0, 0, 0);
      }
    }

    if (t + 1 < NST) swrite(cur ^ 1);
    __syncthreads();
  }

  // epilogue: normalize and store f32
  float* ob = out + ((size_t)(b * SQL + q0 + wave * 16)) * HID;
#pragma unroll
  for (int i = 0; i < 4; i++) {
    float inv = 1.0f / l_[i];
#pragma unroll
    for (int dt = 0; dt < 16; dt++)
      ob[(size_t)(lg * 4 + i) * HID + dt * 16 + lr] = acc[dt][i] * inv;
  }
}

extern "C" void kernel_launch(void* const* d_in, const int* in_sizes, int n_in,
                              void* d_out, int out_size, void* d_ws, size_t ws_size,
                              hipStream_t stream) {
  const float* query = (const float*)d_in[0];
  const float* key   = (const float*)d_in[1];
  const float* value = (const float*)d_in[2];
  const float* Wq = (const float*)d_in[3];
  const float* bq = (const float*)d_in[4];
  const float* Wk = (const float*)d_in[5];
  const float* bk = (const float*)d_in[6];
  const float* Wv = (const float*)d_in[7];
  const float* bv = (const float*)d_in[8];

  char* ws = (char*)d_ws;
  unsigned short* Wb  = (unsigned short*)ws;                       // 3*65536 bf16
  unsigned short* Qb  = (unsigned short*)(ws + 393216);            // 8*2048*256 bf16
  unsigned short* Kb  = Qb + (size_t)NB * SQL * HID;
  unsigned short* Vtb = Kb + (size_t)NB * SKV * HID;               // transposed [b][d][s]

  hipLaunchKernelGGL(wconv_kernel, dim3(768), dim3(256), 0, stream, Wq, Wk, Wv, Wb);
  hipLaunchKernelGGL(proj_kernel, dim3(768), dim3(256), 0, stream,
                     query, key, value, Wb, bq, bk, bv, Qb, Kb, Vtb);
  hipLaunchKernelGGL(attn_kernel, dim3(256), dim3(256), 139264, stream,
                     Qb, Kb, Vtb, (float*)d_out);
}

// Round 2
// 123.372 us; speedup vs baseline: 1.3229x; 1.3229x over previous
//
#include <hip/hip_runtime.h>

#define HID 256
#define NB 8
#define SQL 2048
#define SKV 2048
#define SPLIT 4
#define KPB (SKV / SPLIT)   // 512 keys per block
#define KVB 32              // keys per step
#define NT (KPB / KVB)      // 16 steps
#define NROW (NB * SQL)     // 16384 rows

typedef __attribute__((ext_vector_type(8))) short bf16x8;
typedef __attribute__((ext_vector_type(4))) float f32x4;
typedef __attribute__((ext_vector_type(16))) float f32x16;

static __device__ __forceinline__ unsigned short f2bf(float x) {
  union { float f; unsigned int u; } v; v.f = x;
  unsigned int r = v.u + 0x7FFFu + ((v.u >> 16) & 1u);
  return (unsigned short)(r >> 16);
}

// ---------- P0: convert weight matrices to bf16 ----------
__global__ void wconv_kernel(const float* __restrict__ Wq, const float* __restrict__ Wk,
                             const float* __restrict__ Wv, unsigned short* __restrict__ out) {
  int i = blockIdx.x * blockDim.x + threadIdx.x;
  if (i >= 3 * HID * HID) return;
  const float* src = (i < HID * HID) ? Wq : (i < 2 * HID * HID ? Wk : Wv);
  out[i] = f2bf(src[i & (HID * HID - 1)]);
}

// ---------- P1: QKV projection (bf16 MFMA), V written transposed ----------
__global__ __launch_bounds__(256) void proj_kernel(
    const float* __restrict__ query, const float* __restrict__ key, const float* __restrict__ value,
    const unsigned short* __restrict__ Wb,
    const float* __restrict__ bq, const float* __restrict__ bk, const float* __restrict__ bv,
    unsigned short* __restrict__ Qb, unsigned short* __restrict__ Kb, unsigned short* __restrict__ Vtb) {
  int blk = blockIdx.x;
  int mat = blk >> 8;      // 0:Q 1:K 2:V
  int rem = blk & 255;
  int b = rem >> 5;
  int st = rem & 31;       // 64-row tile
  int tid = threadIdx.x;
  int wave = tid >> 6, lane = tid & 63, lr = lane & 15, lg = lane >> 4;

  const float* X = (mat == 0) ? query : (mat == 1 ? key : value);
  const float* bias = (mat == 0) ? bq : (mat == 1 ? bk : bv);
  const unsigned short* W = Wb + mat * HID * HID;

  int row_a = st * 64 + wave * 16 + lr;
  const float* xrow = X + ((size_t)(b * SQL + row_a)) * HID;
  bf16x8 af[8];
#pragma unroll
  for (int s = 0; s < 8; s++) {
    const float4* p = (const float4*)(xrow + s * 32 + lg * 8);
    float4 x0 = p[0], x1 = p[1];
    bf16x8 a;
    a[0] = (short)f2bf(x0.x); a[1] = (short)f2bf(x0.y); a[2] = (short)f2bf(x0.z); a[3] = (short)f2bf(x0.w);
    a[4] = (short)f2bf(x1.x); a[5] = (short)f2bf(x1.y); a[6] = (short)f2bf(x1.z); a[7] = (short)f2bf(x1.w);
    af[s] = a;
  }
  int row_c = st * 64 + wave * 16 + lg * 4;

#pragma unroll
  for (int eg = 0; eg < 4; eg++) {
    f32x4 a4[4];
#pragma unroll
    for (int e4 = 0; e4 < 4; e4++) a4[e4] = (f32x4){0.f, 0.f, 0.f, 0.f};
#pragma unroll
    for (int sl = 0; sl < 8; sl++) {
#pragma unroll
      for (int e4 = 0; e4 < 4; e4++) {
        const unsigned short* wrow = W + ((eg * 4 + e4) * 16 + lr) * HID;
        bf16x8 bfr = *(const bf16x8*)(wrow + sl * 32 + lg * 8);
        a4[e4] = __builtin_amdgcn_mfma_f32_16x16x32_bf16(af[sl], bfr, a4[e4], 0, 0, 0);
      }
    }
#pragma unroll
    for (int e4 = 0; e4 < 4; e4++) {
      int e = (eg * 4 + e4) * 16 + lr;
      float bv_ = bias[e];
      if (mat < 2) {
        unsigned short* dst = (mat == 0 ? Qb : Kb) + (size_t)(b * SQL) * HID;
#pragma unroll
        for (int i = 0; i < 4; i++)
          dst[(size_t)(row_c + i) * HID + e] = f2bf(a4[e4][i] + bv_);
      } else {
        ushort4 v;
        v.x = f2bf(a4[e4][0] + bv_); v.y = f2bf(a4[e4][1] + bv_);
        v.z = f2bf(a4[e4][2] + bv_); v.w = f2bf(a4[e4][3] + bv_);
        *(ushort4*)(Vtb + ((size_t)(b * HID + e)) * SKV + row_c) = v;
      }
    }
  }
}

// ---------- A: flash attention, split-KV, 32x32 MFMA, P in registers ----------
__global__ __launch_bounds__(256, 2) void attn_kernel(
    const unsigned short* __restrict__ Qb, const unsigned short* __restrict__ Kb,
    const unsigned short* __restrict__ Vtb, unsigned short* __restrict__ Op,
    float* __restrict__ Ml) {
  extern __shared__ char smem[];  // K0[16K] K1[16K] V0[16K] V1[16K]
  int tid = threadIdx.x;
  int wave = tid >> 6, lane = tid & 63, l31 = lane & 31, h = lane >> 5;
  int bid = (blockIdx.x & 7) * 64 + (blockIdx.x >> 3);  // XCD-contiguous (b,s) groups
  int b = bid >> 6, s = (bid >> 4) & 3, qt = bid & 15;
  int qrow0 = qt * 128 + wave * 32;
  int k0 = s * KPB;

  const char* Kc0 = (const char*)(Kb + (size_t)b * SKV * HID) + (size_t)k0 * (HID * 2);
  const char* Vc0 = (const char*)(Vtb + (size_t)b * HID * SKV) + (size_t)k0 * 2;

  // staging source offsets (inverse-swizzled; LDS dest is linear lane order)
  int offK[4], offV[4];
#pragma unroll
  for (int i = 0; i < 4; i++) {
    int g = i * 256 + tid;
    int r = g >> 5, c = g & 31;
    int gr = (c & 24) | ((c ^ (r & 7)) & 7);
    offK[i] = r * 512 + gr * 16;
    int r2 = g >> 3, gp = g & 7;
    int pre = gp ^ (r2 & 7);
    int d = 2 * r2 + (pre >> 2), cc = pre & 3;
    offV[i] = d * (SKV * 2) + cc * 16;
  }

  auto stage = [&](int t, int buf) {
    const char* Ksrc = Kc0 + t * (KVB * HID * 2);
    const char* Vsrc = Vc0 + t * (KVB * 2);
    char* kdst = smem + buf * 16384;
    char* vdst = smem + 32768 + buf * 16384;
#pragma unroll
    for (int i = 0; i < 4; i++)
      __builtin_amdgcn_global_load_lds(
          (const __attribute__((address_space(1))) unsigned int*)(Ksrc + offK[i]),
          (__attribute__((address_space(3))) unsigned int*)(kdst + (i * 256 + tid) * 16),
          16, 0, 0);
#pragma unroll
    for (int i = 0; i < 4; i++)
      __builtin_amdgcn_global_load_lds(
          (const __attribute__((address_space(1))) unsigned int*)(Vsrc + offV[i]),
          (__attribute__((address_space(3))) unsigned int*)(vdst + (i * 256 + tid) * 16),
          16, 0, 0);
  };

  // Q fragments: lane holds Q[q=l31][ks*16 + h*8 .. +7]
  bf16x8 qf[16];
  {
    const unsigned short* qrow = Qb + ((size_t)(b * SQL + qrow0 + l31)) * HID + h * 8;
#pragma unroll
    for (int ks = 0; ks < 16; ks++) qf[ks] = *(const bf16x8*)(qrow + ks * 16);
  }

  f32x16 acc[8];
#pragma unroll
  for (int dt = 0; dt < 8; dt++)
#pragma unroll
    for (int j = 0; j < 16; j++) acc[dt][j] = 0.f;

  float m = -1e30f, l = 0.f;
  const float kC = 1.44269504088896341f / 11.3137084989847604f;  // log2(e)/sqrt(128)

  stage(0, 0);
  __syncthreads();

  for (int t = 0; t < NT; t++) {
    int cur = t & 1;
    if (t + 1 < NT) stage(t + 1, cur ^ 1);
    const char* kb = smem + cur * 16384;
    const char* vb = smem + 32768 + cur * 16384;

    // QK^T (swapped): C[row=key][col=q=l31]
    f32x16 p;
#pragma unroll
    for (int j = 0; j < 16; j++) p[j] = 0.f;
#pragma unroll
    for (int ks = 0; ks < 16; ks++) {
      int gr0 = ks * 2 + h;
      int gr = (gr0 & 24) | ((gr0 ^ (l31 & 7)) & 7);
      bf16x8 kf = *(const bf16x8*)(kb + l31 * 512 + gr * 16);
      p = __builtin_amdgcn_mfma_f32_32x32x16_bf16(kf, qf[ks], p, 0, 0, 0);
    }

    // online softmax, defer-max THR=8 (exp2 domain)
    float tmax = p[0];
#pragma unroll
    for (int j = 1; j < 16; j++) tmax = fmaxf(tmax, p[j]);
    tmax = fmaxf(tmax, __shfl_xor(tmax, 32, 64));
    float msc = tmax * kC;
    if (!__all(msc <= m + 8.0f)) {
      float mn = fmaxf(m, msc);
      float al = exp2f(m - mn);
      l *= al;
      m = mn;
#pragma unroll
      for (int r = 0; r < 16; r++) {
        int qp = (r & 3) + 8 * (r >> 2) + 4 * h;
        float ar = __shfl(al, qp, 64);
#pragma unroll
        for (int dt = 0; dt < 8; dt++) acc[dt][r] *= ar;
      }
    }
#pragma unroll
    for (int j = 0; j < 16; j++) p[j] = exp2f(fmaf(p[j], kC, -m));
    float ts = 0.f;
#pragma unroll
    for (int j = 0; j < 16; j++) ts += p[j];
    ts += __shfl_xor(ts, 32, 64);
    l += ts;

    // P -> A-frags via cvt_pk + permlane32_swap (T12), then PV
#pragma unroll
    for (int k2 = 0; k2 < 2; k2++) {
      unsigned P0, P1, P2, P3;
      asm("v_cvt_pk_bf16_f32 %0, %1, %2" : "=v"(P0) : "v"(p[k2 * 8 + 0]), "v"(p[k2 * 8 + 1]));
      asm("v_cvt_pk_bf16_f32 %0, %1, %2" : "=v"(P1) : "v"(p[k2 * 8 + 2]), "v"(p[k2 * 8 + 3]));
      asm("v_cvt_pk_bf16_f32 %0, %1, %2" : "=v"(P2) : "v"(p[k2 * 8 + 4]), "v"(p[k2 * 8 + 5]));
      asm("v_cvt_pk_bf16_f32 %0, %1, %2" : "=v"(P3) : "v"(p[k2 * 8 + 6]), "v"(p[k2 * 8 + 7]));
      asm("v_permlane32_swap_b32 %0, %1" : "+v"(P0), "+v"(P2));
      asm("v_permlane32_swap_b32 %0, %1" : "+v"(P1), "+v"(P3));
      union { unsigned u[4]; bf16x8 v; } pa;
      pa.u[0] = P0; pa.u[1] = P1; pa.u[2] = P2; pa.u[3] = P3;
#pragma unroll
      for (int dt = 0; dt < 8; dt++) {
        int d = dt * 32 + l31;
        int gp = ((d & 1) * 4 + k2 * 2 + h) ^ ((d >> 1) & 7);
        bf16x8 vf = *(const bf16x8*)(vb + (d >> 1) * 128 + gp * 16);
        acc[dt] = __builtin_amdgcn_mfma_f32_32x32x16_bf16(pa.v, vf, acc[dt], 0, 0, 0);
      }
    }
    __syncthreads();
  }

  // epilogue: write (m,l) + normalized f16 partial O
  if (h == 0) {
    size_t row = (size_t)b * SQL + qrow0 + l31;
    float2 ml; ml.x = m; ml.y = l;
    *(float2*)(Ml + ((size_t)s * NROW + row) * 2) = ml;
  }
#pragma unroll
  for (int r = 0; r < 16; r++) {
    int qp = (r & 3) + 8 * (r >> 2) + 4 * h;
    float linv = 1.0f / __shfl(l, qp, 64);
    size_t row = (size_t)b * SQL + qrow0 + qp;
#pragma unroll
    for (int dt = 0; dt < 8; dt++) {
      union { _Float16 hf; unsigned short u; } cv;
      cv.hf = (_Float16)(acc[dt][r] * linv);
      Op[((size_t)s * NROW + row) * HID + dt * 32 + l31] = cv.u;
    }
  }
}

// ---------- C: combine split partials ----------
__global__ __launch_bounds__(256) void comb_kernel(const unsigned short* __restrict__ Op,
                                                   const float* __restrict__ Ml,
                                                   float* __restrict__ out) {
  int idx = blockIdx.x * 256 + threadIdx.x;
  int row = idx >> 6;
  int d0 = (idx & 63) << 2;
  float mv[SPLIT], lv[SPLIT];
#pragma unroll
  for (int s = 0; s < SPLIT; s++) {
    float2 ml = *(const float2*)(Ml + ((size_t)s * NROW + row) * 2);
    mv[s] = ml.x; lv[s] = ml.y;
  }
  float M = mv[0];
#pragma unroll
  for (int s = 1; s < SPLIT; s++) M = fmaxf(M, mv[s]);
  float W = 0.f, w[SPLIT];
#pragma unroll
  for (int s = 0; s < SPLIT; s++) { w[s] = lv[s] * exp2f(mv[s] - M); W += w[s]; }
  float wi = 1.0f / W;
  float o0 = 0.f, o1 = 0.f, o2 = 0.f, o3 = 0.f;
#pragma unroll
  for (int s = 0; s < SPLIT; s++) {
    ushort4 u = *(const ushort4*)(Op + ((size_t)s * NROW + row) * HID + d0);
    union { unsigned short us; _Float16 hf; } c0, c1, c2, c3;
    c0.us = u.x; c1.us = u.y; c2.us = u.z; c3.us = u.w;
    o0 += w[s] * (float)c0.hf; o1 += w[s] * (float)c1.hf;
    o2 += w[s] * (float)c2.hf; o3 += w[s] * (float)c3.hf;
  }
  float4 res; res.x = o0 * wi; res.y = o1 * wi; res.z = o2 * wi; res.w = o3 * wi;
  *(float4*)(out + (size_t)row * HID + d0) = res;
}

extern "C" void kernel_launch(void* const* d_in, const int* in_sizes, int n_in,
                              void* d_out, int out_size, void* d_ws, size_t ws_size,
                              hipStream_t stream) {
  const float* query = (const float*)d_in[0];
  const float* key   = (const float*)d_in[1];
  const float* value = (const float*)d_in[2];
  const float* Wq = (const float*)d_in[3];
  const float* bq = (const float*)d_in[4];
  const float* Wk = (const float*)d_in[5];
  const float* bk = (const float*)d_in[6];
  const float* Wv = (const float*)d_in[7];
  const float* bv = (const float*)d_in[8];

  char* ws = (char*)d_ws;
  unsigned short* Wb  = (unsigned short*)ws;                        // 3*65536 bf16 = 393216 B
  unsigned short* Qb  = (unsigned short*)(ws + 393216);             // 8.39 MB
  unsigned short* Kb  = Qb + (size_t)NB * SQL * HID;
  unsigned short* Vtb = Kb + (size_t)NB * SKV * HID;                // [b][d][s]
  unsigned short* Op  = Vtb + (size_t)NB * HID * SKV;               // f16 partials 33.55 MB
  float* Ml = (float*)(Op + (size_t)SPLIT * NROW * HID);            // (m,l) per split-row

  hipLaunchKernelGGL(wconv_kernel, dim3(768), dim3(256), 0, stream, Wq, Wk, Wv, Wb);
  hipLaunchKernelGGL(proj_kernel, dim3(768), dim3(256), 0, stream,
                     query, key, value, Wb, bq, bk, bv, Qb, Kb, Vtb);
  hipLaunchKernelGGL(attn_kernel, dim3(512), dim3(256), 65536, stream, Qb, Kb, Vtb, Op, Ml);
  hipLaunchKernelGGL(comb_kernel, dim3(4096), dim3(256), 0, stream, Op, Ml, (float*)d_out);
}

// Round 3
// 107.231 us; speedup vs baseline: 1.5220x; 1.1505x over previous
//
#include <hip/hip_runtime.h>

#define HID 256
#define NB 8
#define SQL 2048
#define SKV 2048
#define SPLIT 4
#define KPB (SKV / SPLIT)   // 512 keys per block
#define KVB 32              // keys per step
#define NT (KPB / KVB)      // 16 steps
#define NROW (NB * SQL)     // 16384 rows

typedef __attribute__((ext_vector_type(8))) short bf16x8;
typedef __attribute__((ext_vector_type(4))) float f32x4;
typedef __attribute__((ext_vector_type(16))) float f32x16;

static __device__ __forceinline__ unsigned short f2bf(float x) {
  union { float f; unsigned int u; } v; v.f = x;
  unsigned int r = v.u + 0x7FFFu + ((v.u >> 16) & 1u);
  return (unsigned short)(r >> 16);
}

// ---------- P0: convert weight matrices to bf16 ----------
__global__ void wconv_kernel(const float* __restrict__ Wq, const float* __restrict__ Wk,
                             const float* __restrict__ Wv, unsigned short* __restrict__ out) {
  int i = blockIdx.x * blockDim.x + threadIdx.x;
  if (i >= 3 * HID * HID) return;
  const float* src = (i < HID * HID) ? Wq : (i < 2 * HID * HID ? Wk : Wv);
  out[i] = f2bf(src[i & (HID * HID - 1)]);
}

// ---------- P1: QKV projection; W-half staged in LDS (swizzled) ----------
__global__ __launch_bounds__(512, 4) void proj_kernel(
    const float* __restrict__ query, const float* __restrict__ key, const float* __restrict__ value,
    const unsigned short* __restrict__ Wb,
    const float* __restrict__ bq, const float* __restrict__ bk, const float* __restrict__ bv,
    unsigned short* __restrict__ Qb, unsigned short* __restrict__ Kb, unsigned short* __restrict__ Vtb) {
  __shared__ __align__(16) char wl[65536];  // W[e0..e0+127][0..255] bf16, XOR-swizzled rows
  int tid = threadIdx.x;
  int wave = tid >> 6, lane = tid & 63, lr = lane & 15, lg = lane >> 4;
  int blk = blockIdx.x;
  int mat = blk >> 8;       // 0:Q 1:K 2:V
  int rem = blk & 255;
  int b = rem >> 5;         // 8
  int rt = (rem >> 1) & 15; // 16 row-tiles of 128
  int et = rem & 1;         // output half

  const float* X = (mat == 0) ? query : (mat == 1 ? key : value);
  const float* bias = (mat == 0) ? bq : (mat == 1 ? bk : bv);
  const char* Wsrc = (const char*)(Wb + mat * HID * HID + et * 128 * HID);

  // stage 64KB of W: linear LDS dest, inverse-swizzled global source (rule 21)
#pragma unroll
  for (int i = 0; i < 8; i++) {
    int c = i * 512 + tid;            // 16B chunk index, 0..4095
    int e = c >> 5;                   // local output row 0..127
    int glo = e * 512 + (((c & 31) ^ (e & 7)) << 4);
    __builtin_amdgcn_global_load_lds(
        (const __attribute__((address_space(1))) unsigned int*)(Wsrc + glo),
        (__attribute__((address_space(3))) unsigned int*)(wl + c * 16), 16, 0, 0);
  }

  // A fragments: 16 rows per wave, f32 -> bf16
  int row_a = rt * 128 + wave * 16 + lr;
  const float* xrow = X + ((size_t)(b * SQL + row_a)) * HID;
  bf16x8 af[8];
#pragma unroll
  for (int s = 0; s < 8; s++) {
    const float4* p = (const float4*)(xrow + s * 32 + lg * 8);
    float4 x0 = p[0], x1 = p[1];
    bf16x8 a;
    a[0] = (short)f2bf(x0.x); a[1] = (short)f2bf(x0.y); a[2] = (short)f2bf(x0.z); a[3] = (short)f2bf(x0.w);
    a[4] = (short)f2bf(x1.x); a[5] = (short)f2bf(x1.y); a[6] = (short)f2bf(x1.z); a[7] = (short)f2bf(x1.w);
    af[s] = a;
  }
  __syncthreads();  // single full drain: W staged, visible to all waves

  int row_c = rt * 128 + wave * 16 + lg * 4;
#pragma unroll
  for (int eo = 0; eo < 8; eo++) {
    f32x4 acc = (f32x4){0.f, 0.f, 0.f, 0.f};
    int eL = eo * 16 + lr;
#pragma unroll
    for (int sl = 0; sl < 8; sl++) {
      bf16x8 bfr = *(const bf16x8*)(wl + eL * 512 + (((sl * 4 + lg) ^ (eL & 7)) << 4));
      acc = __builtin_amdgcn_mfma_f32_16x16x32_bf16(af[sl], bfr, acc, 0, 0, 0);
    }
    int e = et * 128 + eo * 16 + lr;
    float bv_ = bias[e];
    if (mat < 2) {
      unsigned short* dst = (mat == 0 ? Qb : Kb) + (size_t)(b * SQL) * HID;
#pragma unroll
      for (int i = 0; i < 4; i++)
        dst[(size_t)(row_c + i) * HID + e] = f2bf(acc[i] + bv_);
    } else {
      ushort4 v;
      v.x = f2bf(acc[0] + bv_); v.y = f2bf(acc[1] + bv_);
      v.z = f2bf(acc[2] + bv_); v.w = f2bf(acc[3] + bv_);
      *(ushort4*)(Vtb + ((size_t)(b * HID + e)) * SKV + row_c) = v;
    }
  }
}

// ---------- A: flash attention, counted-vmcnt 2-phase pipeline ----------
__global__ __launch_bounds__(256, 2) void attn_kernel(
    const unsigned short* __restrict__ Qb, const unsigned short* __restrict__ Kb,
    const unsigned short* __restrict__ Vtb, unsigned short* __restrict__ Op,
    float* __restrict__ Ml) {
  __shared__ __align__(16) char KA[16384];
  __shared__ __align__(16) char KB[16384];
  __shared__ __align__(16) char VA[16384];
  __shared__ __align__(16) char VB[16384];
  int tid = threadIdx.x;
  int wave = tid >> 6, lane = tid & 63, l31 = lane & 31, h = lane >> 5;
  int bid = (blockIdx.x & 7) * 64 + (blockIdx.x >> 3);  // XCD-contiguous groups
  int b = bid >> 6, s = (bid >> 4) & 3, qt = bid & 15;
  int qrow0 = qt * 128 + wave * 32;
  int k0 = s * KPB;

  const char* Kc0 = (const char*)(Kb + (size_t)b * SKV * HID) + (size_t)k0 * (HID * 2);
  const char* Vc0 = (const char*)(Vtb + (size_t)b * HID * SKV) + (size_t)k0 * 2;

  // staging source offsets (inverse-swizzled; LDS dest linear)
  int offK[4], offV[4];
#pragma unroll
  for (int i = 0; i < 4; i++) {
    int g = i * 256 + tid;
    int r = g >> 5, c = g & 31;
    int gr = (c & 24) | ((c ^ (r & 7)) & 7);
    offK[i] = r * 512 + gr * 16;
    int r2 = g >> 3, gp = g & 7;
    int pre = gp ^ (r2 & 7);
    int d = 2 * r2 + (pre >> 2), cc = pre & 3;
    offV[i] = d * (SKV * 2) + cc * 16;
  }

  auto stage = [&](int t, char* kdst, char* vdst) {
    const char* Ksrc = Kc0 + t * (KVB * HID * 2);
    const char* Vsrc = Vc0 + t * (KVB * 2);
#pragma unroll
    for (int i = 0; i < 4; i++)
      __builtin_amdgcn_global_load_lds(
          (const __attribute__((address_space(1))) unsigned int*)(Ksrc + offK[i]),
          (__attribute__((address_space(3))) unsigned int*)(kdst + (i * 256 + tid) * 16),
          16, 0, 0);
#pragma unroll
    for (int i = 0; i < 4; i++)
      __builtin_amdgcn_global_load_lds(
          (const __attribute__((address_space(1))) unsigned int*)(Vsrc + offV[i]),
          (__attribute__((address_space(3))) unsigned int*)(vdst + (i * 256 + tid) * 16),
          16, 0, 0);
  };

  // Q fragments
  bf16x8 qf[16];
  {
    const unsigned short* qrow = Qb + ((size_t)(b * SQL + qrow0 + l31)) * HID + h * 8;
#pragma unroll
    for (int ks = 0; ks < 16; ks++) qf[ks] = *(const bf16x8*)(qrow + ks * 16);
  }

  f32x16 acc[8];
#pragma unroll
  for (int dt = 0; dt < 8; dt++)
#pragma unroll
    for (int j = 0; j < 16; j++) acc[dt][j] = 0.f;

  float m = -1e30f, l = 0.f;
  const float kC = 1.44269504088896341f / 11.3137084989847604f;  // log2(e)/sqrt(128)

  auto step = [&](const char* kb, const char* vb) {
    // QK^T (swapped): C[row=key][col=q=l31]
    f32x16 p;
#pragma unroll
    for (int j = 0; j < 16; j++) p[j] = 0.f;
    __builtin_amdgcn_s_setprio(1);
#pragma unroll
    for (int ks = 0; ks < 16; ks++) {
      int gr0 = ks * 2 + h;
      int gr = (gr0 & 24) | ((gr0 ^ (l31 & 7)) & 7);
      bf16x8 kf = *(const bf16x8*)(kb + l31 * 512 + gr * 16);
      p = __builtin_amdgcn_mfma_f32_32x32x16_bf16(kf, qf[ks], p, 0, 0, 0);
    }
    __builtin_amdgcn_s_setprio(0);

    // online softmax, defer-max THR=8 (exp2 domain)
    float tmax = p[0];
#pragma unroll
    for (int j = 1; j < 16; j++) tmax = fmaxf(tmax, p[j]);
    tmax = fmaxf(tmax, __shfl_xor(tmax, 32, 64));
    float msc = tmax * kC;
    if (!__all(msc <= m + 8.0f)) {
      float mn = fmaxf(m, msc);
      float al = exp2f(m - mn);
      l *= al;
      m = mn;
#pragma unroll
      for (int r = 0; r < 16; r++) {
        int qp = (r & 3) + 8 * (r >> 2) + 4 * h;
        float ar = __shfl(al, qp, 64);
#pragma unroll
        for (int dt = 0; dt < 8; dt++) acc[dt][r] *= ar;
      }
    }
#pragma unroll
    for (int j = 0; j < 16; j++) p[j] = exp2f(fmaf(p[j], kC, -m));
    float ts = 0.f;
#pragma unroll
    for (int j = 0; j < 16; j++) ts += p[j];
    ts += __shfl_xor(ts, 32, 64);
    l += ts;

    // P -> A-frags via cvt_pk + permlane32_swap (T12), then PV
#pragma unroll
    for (int k2 = 0; k2 < 2; k2++) {
      unsigned P0, P1, P2, P3;
      asm("v_cvt_pk_bf16_f32 %0, %1, %2" : "=v"(P0) : "v"(p[k2 * 8 + 0]), "v"(p[k2 * 8 + 1]));
      asm("v_cvt_pk_bf16_f32 %0, %1, %2" : "=v"(P1) : "v"(p[k2 * 8 + 2]), "v"(p[k2 * 8 + 3]));
      asm("v_cvt_pk_bf16_f32 %0, %1, %2" : "=v"(P2) : "v"(p[k2 * 8 + 4]), "v"(p[k2 * 8 + 5]));
      asm("v_cvt_pk_bf16_f32 %0, %1, %2" : "=v"(P3) : "v"(p[k2 * 8 + 6]), "v"(p[k2 * 8 + 7]));
      asm("v_permlane32_swap_b32 %0, %1" : "+v"(P0), "+v"(P2));
      asm("v_permlane32_swap_b32 %0, %1" : "+v"(P1), "+v"(P3));
      union { unsigned u[4]; bf16x8 v; } pa;
      pa.u[0] = P0; pa.u[1] = P1; pa.u[2] = P2; pa.u[3] = P3;
      __builtin_amdgcn_s_setprio(1);
#pragma unroll
      for (int dt = 0; dt < 8; dt++) {
        int d = dt * 32 + l31;
        int gp = ((d & 1) * 4 + k2 * 2 + h) ^ ((d >> 1) & 7);
        bf16x8 vf = *(const bf16x8*)(vb + (d >> 1) * 128 + gp * 16);
        acc[dt] = __builtin_amdgcn_mfma_f32_32x32x16_bf16(pa.v, vf, acc[dt], 0, 0, 0);
      }
      __builtin_amdgcn_s_setprio(0);
    }
  };

  stage(0, KA, VA);
  for (int it = 0; it < 8; ++it) {
    // phase A: compute steps 2it from (KA,VA), prefetch 2it+1 -> (KB,VB)
    stage(it * 2 + 1, KB, VB);
    asm volatile("s_waitcnt vmcnt(8)" ::: "memory");  // my (KA,VA) loads landed
    __builtin_amdgcn_s_barrier();                     // everyone's landed
    __builtin_amdgcn_sched_barrier(0);
    step(KA, VA);
    __builtin_amdgcn_s_barrier();                     // all done reading (KA,VA)
    // phase B
    stage((it * 2 + 2) & 15, KA, VA);                 // wrap refetch on last iter (unused)
    asm volatile("s_waitcnt vmcnt(8)" ::: "memory");
    __builtin_amdgcn_s_barrier();
    __builtin_amdgcn_sched_barrier(0);
    step(KB, VB);
    __builtin_amdgcn_s_barrier();
  }

  // epilogue: write (m,l) + normalized f16 partial O
  if (h == 0) {
    size_t row = (size_t)b * SQL + qrow0 + l31;
    float2 ml; ml.x = m; ml.y = l;
    *(float2*)(Ml + ((size_t)s * NROW + row) * 2) = ml;
  }
#pragma unroll
  for (int r = 0; r < 16; r++) {
    int qp = (r & 3) + 8 * (r >> 2) + 4 * h;
    float linv = 1.0f / __shfl(l, qp, 64);
    size_t row = (size_t)b * SQL + qrow0 + qp;
#pragma unroll
    for (int dt = 0; dt < 8; dt++) {
      union { _Float16 hf; unsigned short u; } cv;
      cv.hf = (_Float16)(acc[dt][r] * linv);
      Op[((size_t)s * NROW + row) * HID + dt * 32 + l31] = cv.u;
    }
  }
}

// ---------- C: combine split partials ----------
__global__ __launch_bounds__(256) void comb_kernel(const unsigned short* __restrict__ Op,
                                                   const float* __restrict__ Ml,
                                                   float* __restrict__ out) {
  int idx = blockIdx.x * 256 + threadIdx.x;
  int row = idx >> 6;
  int d0 = (idx & 63) << 2;
  float mv[SPLIT], lv[SPLIT];
#pragma unroll
  for (int s = 0; s < SPLIT; s++) {
    float2 ml = *(const float2*)(Ml + ((size_t)s * NROW + row) * 2);
    mv[s] = ml.x; lv[s] = ml.y;
  }
  float M = mv[0];
#pragma unroll
  for (int s = 1; s < SPLIT; s++) M = fmaxf(M, mv[s]);
  float W = 0.f, w[SPLIT];
#pragma unroll
  for (int s = 0; s < SPLIT; s++) { w[s] = lv[s] * exp2f(mv[s] - M); W += w[s]; }
  float wi = 1.0f / W;
  float o0 = 0.f, o1 = 0.f, o2 = 0.f, o3 = 0.f;
#pragma unroll
  for (int s = 0; s < SPLIT; s++) {
    ushort4 u = *(const ushort4*)(Op + ((size_t)s * NROW + row) * HID + d0);
    union { unsigned short us; _Float16 hf; } c0, c1, c2, c3;
    c0.us = u.x; c1.us = u.y; c2.us = u.z; c3.us = u.w;
    o0 += w[s] * (float)c0.hf; o1 += w[s] * (float)c1.hf;
    o2 += w[s] * (float)c2.hf; o3 += w[s] * (float)c3.hf;
  }
  float4 res; res.x = o0 * wi; res.y = o1 * wi; res.z = o2 * wi; res.w = o3 * wi;
  *(float4*)(out + (size_t)row * HID + d0) = res;
}

extern "C" void kernel_launch(void* const* d_in, const int* in_sizes, int n_in,
                              void* d_out, int out_size, void* d_ws, size_t ws_size,
                              hipStream_t stream) {
  const float* query = (const float*)d_in[0];
  const float* key   = (const float*)d_in[1];
  const float* value = (const float*)d_in[2];
  const float* Wq = (const float*)d_in[3];
  const float* bq = (const float*)d_in[4];
  const float* Wk = (const float*)d_in[5];
  const float* bk = (const float*)d_in[6];
  const float* Wv = (const float*)d_in[7];
  const float* bv = (const float*)d_in[8];

  char* ws = (char*)d_ws;
  unsigned short* Wb  = (unsigned short*)ws;                        // 393216 B
  unsigned short* Qb  = (unsigned short*)(ws + 393216);
  unsigned short* Kb  = Qb + (size_t)NB * SQL * HID;
  unsigned short* Vtb = Kb + (size_t)NB * SKV * HID;                // [b][d][s]
  unsigned short* Op  = Vtb + (size_t)NB * HID * SKV;               // f16 partials
  float* Ml = (float*)(Op + (size_t)SPLIT * NROW * HID);            // (m,l)

  hipLaunchKernelGGL(wconv_kernel, dim3(768), dim3(256), 0, stream, Wq, Wk, Wv, Wb);
  hipLaunchKernelGGL(proj_kernel, dim3(768), dim3(512), 0, stream,
                     query, key, value, Wb, bq, bk, bv, Qb, Kb, Vtb);
  hipLaunchKernelGGL(attn_kernel, dim3(512), dim3(256), 0, stream, Qb, Kb, Vtb, Op, Ml);
  hipLaunchKernelGGL(comb_kernel, dim3(4096), dim3(256), 0, stream, Op, Ml, (float*)d_out);
}